// Round 1
// baseline (397.543 us; speedup 1.0000x reference)
//
#include <hip/hip_runtime.h>
#include <math.h>

// Problem constants (fixed by reference)
#define BB 4
#define SS 4096
#define DD 64
#define HH 16
#define DH 1024
#define PI_C 3.1415f

#define TS1 32      // phase-1 s-tile
#define NC  16      // phase-1 chunks over S
#define CHUNK (SS/NC)   // 256
#define TS2 32      // phase-2 s-tile
#define PAD 68      // padded LDS row (floats), 16B-aligned rows, bank-shifted

// ws layout (floats):
//   kv    [B*H][64*64]   @ 0
//   kvs   [B*H][64*64]   @ 262144
//   ksum  [B*H][64]      @ 524288
//   kssum [B*H][64]      @ 528384
//   total 532480 floats = 2.13 MB

__device__ __forceinline__ void fma4(float* acc, float s, float4 b) {
    acc[0] = fmaf(s, b.x, acc[0]);
    acc[1] = fmaf(s, b.y, acc[1]);
    acc[2] = fmaf(s, b.z, acc[2]);
    acc[3] = fmaf(s, b.w, acc[3]);
}

__global__ __launch_bounds__(256) void k_zero(float* __restrict__ p) {
    int i = blockIdx.x * 256 + threadIdx.x;   // 520*256 = 133120 float4 = 532480 floats
    reinterpret_cast<float4*>(p)[i] = make_float4(0.f, 0.f, 0.f, 0.f);
}

// ---------------- Phase 1: kv / kvs / ksum / kssum accumulation -------------
__global__ __launch_bounds__(256) void k_phase1(
    const float* __restrict__ key, const float* __restrict__ value,
    const float* __restrict__ wk_w, const float* __restrict__ wk_b,
    const float* __restrict__ wv_w, const float* __restrict__ wv_b,
    float* __restrict__ kv, float* __restrict__ kvs,
    float* __restrict__ ksum, float* __restrict__ kssum)
{
    const int chunk = blockIdx.x;          // 0..NC-1
    const int h     = blockIdx.y;          // 0..H-1
    const int b     = blockIdx.z;          // 0..B-1
    const int t     = threadIdx.x;         // 0..255
    const int tx    = t & 15;              // col group for proj GEMM
    const int ty    = t >> 4;              // 0..15 -> rows 2ty,2ty+1
    const int tx4   = tx * 4;
    const int z     = t & 63;              // accum col
    const int xg    = t >> 6;              // accum row group (0..3), x in [16xg,16xg+16)

    __shared__ float swk[DD][DD];          // swk[d][x]
    __shared__ float swv[DD][DD];
    __shared__ float sink[TS1][PAD];
    __shared__ float sinv[TS1][PAD];
    __shared__ float skp[TS1][PAD];        // k' (elu+1)
    __shared__ float svp[TS1][PAD];        // v projected
    __shared__ float sbk[DD], sbv[DD];
    __shared__ float ssin[TS1];

    // weights -> LDS (64x64 block of wk_w / wv_w for this head)
    for (int i = t; i < DD * DD / 4; i += 256) {
        int row = i >> 4, c4 = i & 15;
        reinterpret_cast<float4*>(&swk[row][0])[c4] =
            reinterpret_cast<const float4*>(wk_w + row * DH + h * DD)[c4];
        reinterpret_cast<float4*>(&swv[row][0])[c4] =
            reinterpret_cast<const float4*>(wv_w + row * DH + h * DD)[c4];
    }
    if (t < DD) { sbk[t] = wk_b[h * DD + t]; sbv[t] = wv_b[h * DD + t]; }

    float akv[16], akvs[16];
#pragma unroll
    for (int i = 0; i < 16; ++i) { akv[i] = 0.f; akvs[i] = 0.f; }
    float aks = 0.f, akss = 0.f;

    const int r0 = 2 * ty, r1 = 2 * ty + 1;

    for (int tile = 0; tile < CHUNK / TS1; ++tile) {
        const int s0 = chunk * CHUNK + tile * TS1;
        // stage input tiles (fully contiguous & coalesced)
        for (int i = t; i < TS1 * 16; i += 256) {
            int r = i >> 4, c4 = i & 15;
            reinterpret_cast<float4*>(&sink[r][0])[c4] =
                reinterpret_cast<const float4*>(key + ((size_t)b * SS + s0 + r) * DD)[c4];
            reinterpret_cast<float4*>(&sinv[r][0])[c4] =
                reinterpret_cast<const float4*>(value + ((size_t)b * SS + s0 + r) * DD)[c4];
        }
        if (t < TS1) ssin[t] = sinf((PI_C * (float)(s0 + t)) / (float)SS);
        __syncthreads();

        // project K and V: (32x64) @ (64x64); thread -> 2 rows x 4 cols each
        float aK0[4] = {0,0,0,0}, aK1[4] = {0,0,0,0};
        float aV0[4] = {0,0,0,0}, aV1[4] = {0,0,0,0};
#pragma unroll 4
        for (int d4 = 0; d4 < 16; ++d4) {
            const int d = d4 * 4;
            float4 ak0 = *reinterpret_cast<const float4*>(&sink[r0][d]);
            float4 ak1 = *reinterpret_cast<const float4*>(&sink[r1][d]);
            float4 bk0 = *reinterpret_cast<const float4*>(&swk[d + 0][tx4]);
            float4 bk1 = *reinterpret_cast<const float4*>(&swk[d + 1][tx4]);
            float4 bk2 = *reinterpret_cast<const float4*>(&swk[d + 2][tx4]);
            float4 bk3 = *reinterpret_cast<const float4*>(&swk[d + 3][tx4]);
            fma4(aK0, ak0.x, bk0); fma4(aK0, ak0.y, bk1); fma4(aK0, ak0.z, bk2); fma4(aK0, ak0.w, bk3);
            fma4(aK1, ak1.x, bk0); fma4(aK1, ak1.y, bk1); fma4(aK1, ak1.z, bk2); fma4(aK1, ak1.w, bk3);
            float4 av0 = *reinterpret_cast<const float4*>(&sinv[r0][d]);
            float4 av1 = *reinterpret_cast<const float4*>(&sinv[r1][d]);
            float4 bv0 = *reinterpret_cast<const float4*>(&swv[d + 0][tx4]);
            float4 bv1 = *reinterpret_cast<const float4*>(&swv[d + 1][tx4]);
            float4 bv2 = *reinterpret_cast<const float4*>(&swv[d + 2][tx4]);
            float4 bv3 = *reinterpret_cast<const float4*>(&swv[d + 3][tx4]);
            fma4(aV0, av0.x, bv0); fma4(aV0, av0.y, bv1); fma4(aV0, av0.z, bv2); fma4(aV0, av0.w, bv3);
            fma4(aV1, av1.x, bv0); fma4(aV1, av1.y, bv1); fma4(aV1, av1.z, bv2); fma4(aV1, av1.w, bv3);
        }
        // bias + elu+1 (k only), write projected tiles
        {
            float4 bk = *reinterpret_cast<const float4*>(&sbk[tx4]);
            float4 bv = *reinterpret_cast<const float4*>(&sbv[tx4]);
            float k00 = aK0[0] + bk.x, k01 = aK0[1] + bk.y, k02 = aK0[2] + bk.z, k03 = aK0[3] + bk.w;
            float k10 = aK1[0] + bk.x, k11 = aK1[1] + bk.y, k12 = aK1[2] + bk.z, k13 = aK1[3] + bk.w;
            k00 = k00 > 0.f ? k00 + 1.f : expf(k00);
            k01 = k01 > 0.f ? k01 + 1.f : expf(k01);
            k02 = k02 > 0.f ? k02 + 1.f : expf(k02);
            k03 = k03 > 0.f ? k03 + 1.f : expf(k03);
            k10 = k10 > 0.f ? k10 + 1.f : expf(k10);
            k11 = k11 > 0.f ? k11 + 1.f : expf(k11);
            k12 = k12 > 0.f ? k12 + 1.f : expf(k12);
            k13 = k13 > 0.f ? k13 + 1.f : expf(k13);
            *reinterpret_cast<float4*>(&skp[r0][tx4]) = make_float4(k00, k01, k02, k03);
            *reinterpret_cast<float4*>(&skp[r1][tx4]) = make_float4(k10, k11, k12, k13);
            *reinterpret_cast<float4*>(&svp[r0][tx4]) =
                make_float4(aV0[0] + bv.x, aV0[1] + bv.y, aV0[2] + bv.z, aV0[3] + bv.w);
            *reinterpret_cast<float4*>(&svp[r1][tx4]) =
                make_float4(aV1[0] + bv.x, aV1[1] + bv.y, aV1[2] + bv.z, aV1[3] + bv.w);
        }
        __syncthreads();

        // rank-1 accumulation over the 32 staged rows
#pragma unroll 4
        for (int si = 0; si < TS1; ++si) {
            float sn  = ssin[si];
            float vz  = svp[si][z];
            float vzs = vz * sn;
            float4 k0 = *reinterpret_cast<const float4*>(&skp[si][xg * 16 + 0]);   // wave-uniform (broadcast)
            float4 k1 = *reinterpret_cast<const float4*>(&skp[si][xg * 16 + 4]);
            float4 k2 = *reinterpret_cast<const float4*>(&skp[si][xg * 16 + 8]);
            float4 k3 = *reinterpret_cast<const float4*>(&skp[si][xg * 16 + 12]);
            fma4(&akv[0],  k0.x, make_float4(0,0,0,0)); // (placeholder removed below)
            // unrolled accumulate
            akv[0]  = fmaf(k0.x, vz,  akv[0]);  akvs[0]  = fmaf(k0.x, vzs, akvs[0]);
            akv[1]  = fmaf(k0.y, vz,  akv[1]);  akvs[1]  = fmaf(k0.y, vzs, akvs[1]);
            akv[2]  = fmaf(k0.z, vz,  akv[2]);  akvs[2]  = fmaf(k0.z, vzs, akvs[2]);
            akv[3]  = fmaf(k0.w, vz,  akv[3]);  akvs[3]  = fmaf(k0.w, vzs, akvs[3]);
            akv[4]  = fmaf(k1.x, vz,  akv[4]);  akvs[4]  = fmaf(k1.x, vzs, akvs[4]);
            akv[5]  = fmaf(k1.y, vz,  akv[5]);  akvs[5]  = fmaf(k1.y, vzs, akvs[5]);
            akv[6]  = fmaf(k1.z, vz,  akv[6]);  akvs[6]  = fmaf(k1.z, vzs, akvs[6]);
            akv[7]  = fmaf(k1.w, vz,  akv[7]);  akvs[7]  = fmaf(k1.w, vzs, akvs[7]);
            akv[8]  = fmaf(k2.x, vz,  akv[8]);  akvs[8]  = fmaf(k2.x, vzs, akvs[8]);
            akv[9]  = fmaf(k2.y, vz,  akv[9]);  akvs[9]  = fmaf(k2.y, vzs, akvs[9]);
            akv[10] = fmaf(k2.z, vz,  akv[10]); akvs[10] = fmaf(k2.z, vzs, akvs[10]);
            akv[11] = fmaf(k2.w, vz,  akv[11]); akvs[11] = fmaf(k2.w, vzs, akvs[11]);
            akv[12] = fmaf(k3.x, vz,  akv[12]); akvs[12] = fmaf(k3.x, vzs, akvs[12]);
            akv[13] = fmaf(k3.y, vz,  akv[13]); akvs[13] = fmaf(k3.y, vzs, akvs[13]);
            akv[14] = fmaf(k3.z, vz,  akv[14]); akvs[14] = fmaf(k3.z, vzs, akvs[14]);
            akv[15] = fmaf(k3.w, vz,  akv[15]); akvs[15] = fmaf(k3.w, vzs, akvs[15]);
            if (xg == (si & 3)) {              // one wave per si handles ksum
                float kx = skp[si][z];
                aks  += kx;
                akss  = fmaf(kx, sn, akss);
            }
        }
        __syncthreads();
    }

    // commit (device-scope atomics; combined across NC chunk-blocks)
    float* kvp  = kv  + ((size_t)(b * HH + h)) * DD * DD;
    float* kvsp = kvs + ((size_t)(b * HH + h)) * DD * DD;
#pragma unroll
    for (int i = 0; i < 16; ++i) {
        atomicAdd(&kvp[(xg * 16 + i) * DD + z], akv[i]);
        atomicAdd(&kvsp[(xg * 16 + i) * DD + z], akvs[i]);
    }
    atomicAdd(&ksum[((size_t)(b * HH + h)) * DD + z], aks);
    atomicAdd(&kssum[((size_t)(b * HH + h)) * DD + z], akss);
}

// ---------------- Phase 2: q-proj, num/den, dense -----------------
__global__ __launch_bounds__(256) void k_phase2(
    const float* __restrict__ query,
    const float* __restrict__ wq_w, const float* __restrict__ wq_b,
    const float* __restrict__ kv, const float* __restrict__ kvs,
    const float* __restrict__ ksum, const float* __restrict__ kssum,
    const float* __restrict__ dense_w, const float* __restrict__ dense_b,
    float* __restrict__ out)
{
    const int st = blockIdx.x;             // 0..S/TS2-1
    const int b  = blockIdx.y;
    const int s0 = st * TS2;
    const int t  = threadIdx.x;
    const int tx = t & 15, ty = t >> 4;
    const int tx4 = tx * 4;
    const int r0 = 2 * ty, r1 = 2 * ty + 1;

    __shared__ float swq[DD][DD];
    __shared__ float skv[DD][DD];
    __shared__ float skvs[DD][DD];
    __shared__ float swd[DD][DD];
    __shared__ float sq[TS2][PAD];
    __shared__ float sks[DD], skss[DD], sbq[DD];
    __shared__ float scc[TS2];

    if (t < TS2) {
        float p = (PI_C * (float)(s0 + t)) / (float)SS;
        scc[t] = cosf(p) + sinf(p);
    }
    __syncthreads();
    const float cc0 = scc[r0], cc1 = scc[r1];

    float oacc0[4] = {0,0,0,0}, oacc1[4] = {0,0,0,0};

    for (int h = 0; h < HH; ++h) {
        const float* kvp  = kv  + ((size_t)(b * HH + h)) * DD * DD;
        const float* kvsp = kvs + ((size_t)(b * HH + h)) * DD * DD;
        for (int i = t; i < DD * DD / 4; i += 256) {
            int row = i >> 4, c4 = i & 15;
            reinterpret_cast<float4*>(&swq[row][0])[c4] =
                reinterpret_cast<const float4*>(wq_w + row * DH + h * DD)[c4];
            reinterpret_cast<float4*>(&skv[row][0])[c4] =
                reinterpret_cast<const float4*>(kvp + row * DD)[c4];
            reinterpret_cast<float4*>(&skvs[row][0])[c4] =
                reinterpret_cast<const float4*>(kvsp + row * DD)[c4];
            reinterpret_cast<float4*>(&swd[row][0])[c4] =
                reinterpret_cast<const float4*>(dense_w + ((size_t)(h * DD) + row) * DD)[c4];
        }
        for (int i = t; i < TS2 * 16; i += 256) {
            int r = i >> 4, c4 = i & 15;
            reinterpret_cast<float4*>(&sq[r][0])[c4] =
                reinterpret_cast<const float4*>(query + ((size_t)b * SS + s0 + r) * DD)[c4];
        }
        if (t < DD) {
            sks[t]  = ksum[((size_t)(b * HH + h)) * DD + t];
            skss[t] = kssum[((size_t)(b * HH + h)) * DD + t];
            sbq[t]  = wq_b[h * DD + t];
        }
        __syncthreads();

        // q projection (32x64)@(64x64) -> regs
        float aq0[4] = {0,0,0,0}, aq1[4] = {0,0,0,0};
#pragma unroll 4
        for (int d4 = 0; d4 < 16; ++d4) {
            const int d = d4 * 4;
            float4 a0 = *reinterpret_cast<const float4*>(&sq[r0][d]);
            float4 a1 = *reinterpret_cast<const float4*>(&sq[r1][d]);
            float4 b0 = *reinterpret_cast<const float4*>(&swq[d + 0][tx4]);
            float4 b1 = *reinterpret_cast<const float4*>(&swq[d + 1][tx4]);
            float4 b2 = *reinterpret_cast<const float4*>(&swq[d + 2][tx4]);
            float4 b3 = *reinterpret_cast<const float4*>(&swq[d + 3][tx4]);
            fma4(aq0, a0.x, b0); fma4(aq0, a0.y, b1); fma4(aq0, a0.z, b2); fma4(aq0, a0.w, b3);
            fma4(aq1, a1.x, b0); fma4(aq1, a1.y, b1); fma4(aq1, a1.z, b2); fma4(aq1, a1.w, b3);
        }
        float4 bq = *reinterpret_cast<const float4*>(&sbq[tx4]);
        float q00 = aq0[0] + bq.x, q01 = aq0[1] + bq.y, q02 = aq0[2] + bq.z, q03 = aq0[3] + bq.w;
        float q10 = aq1[0] + bq.x, q11 = aq1[1] + bq.y, q12 = aq1[2] + bq.z, q13 = aq1[3] + bq.w;
        q00 = q00 > 0.f ? q00 + 1.f : expf(q00);
        q01 = q01 > 0.f ? q01 + 1.f : expf(q01);
        q02 = q02 > 0.f ? q02 + 1.f : expf(q02);
        q03 = q03 > 0.f ? q03 + 1.f : expf(q03);
        q10 = q10 > 0.f ? q10 + 1.f : expf(q10);
        q11 = q11 > 0.f ? q11 + 1.f : expf(q11);
        q12 = q12 > 0.f ? q12 + 1.f : expf(q12);
        q13 = q13 > 0.f ? q13 + 1.f : expf(q13);

        __syncthreads();   // all proj reads of sq done -> safe to overwrite with q'
        *reinterpret_cast<float4*>(&sq[r0][0] + tx4) = make_float4(q00, q01, q02, q03);
        *reinterpret_cast<float4*>(&sq[r1][0] + tx4) = make_float4(q10, q11, q12, q13);
        __syncthreads();

        // denominator: per-thread partial over its 4 x's, butterfly over 16 tx lanes
        float4 kx  = *reinterpret_cast<const float4*>(&sks[tx4]);
        float4 kxs = *reinterpret_cast<const float4*>(&skss[tx4]);
        float d0 = q00 * fmaf(cc0, kxs.x, kx.x) + q01 * fmaf(cc0, kxs.y, kx.y)
                 + q02 * fmaf(cc0, kxs.z, kx.z) + q03 * fmaf(cc0, kxs.w, kx.w);
        float d1 = q10 * fmaf(cc1, kxs.x, kx.x) + q11 * fmaf(cc1, kxs.y, kx.y)
                 + q12 * fmaf(cc1, kxs.z, kx.z) + q13 * fmaf(cc1, kxs.w, kx.w);
#pragma unroll
        for (int m = 1; m <= 8; m <<= 1) {
            d0 += __shfl_xor(d0, m, 64);
            d1 += __shfl_xor(d1, m, 64);
        }
        const float inv0 = 1.0f / (d0 + 1e-5f);
        const float inv1 = 1.0f / (d1 + 1e-5f);

        // numerator GEMM: O[r][c] = sum_x q'[r][x] * (kv[x][c] + cc_r*kvs[x][c])
        float ao0[4] = {0,0,0,0}, ao1[4] = {0,0,0,0};
#pragma unroll 4
        for (int x = 0; x < DD; ++x) {
            float qa = sq[r0][x], qb = sq[r1][x];
            float qac = qa * cc0, qbc = qb * cc1;
            float4 kvv  = *reinterpret_cast<const float4*>(&skv[x][tx4]);
            float4 kvsv = *reinterpret_cast<const float4*>(&skvs[x][tx4]);
            fma4(ao0, qa, kvv); fma4(ao0, qac, kvsv);
            fma4(ao1, qb, kvv); fma4(ao1, qbc, kvsv);
        }
        __syncthreads();   // all num reads of sq done -> overwrite with O
        *reinterpret_cast<float4*>(&sq[r0][0] + tx4) =
            make_float4(ao0[0] * inv0, ao0[1] * inv0, ao0[2] * inv0, ao0[3] * inv0);
        *reinterpret_cast<float4*>(&sq[r1][0] + tx4) =
            make_float4(ao1[0] * inv1, ao1[1] * inv1, ao1[2] * inv1, ao1[3] * inv1);
        __syncthreads();

        // dense accumulation: oacc[r][c] += sum_z O[r][z] * wd[z][c]
#pragma unroll 4
        for (int zz = 0; zz < DD; ++zz) {
            float o0 = sq[r0][zz], o1 = sq[r1][zz];
            float4 wdv = *reinterpret_cast<const float4*>(&swd[zz][tx4]);
            fma4(oacc0, o0, wdv);
            fma4(oacc1, o1, wdv);
        }
        __syncthreads();   // before next head's staging overwrites LDS
    }

    float4 db = *reinterpret_cast<const float4*>(dense_b + tx4);
    float4 o0 = make_float4(oacc0[0] + db.x, oacc0[1] + db.y, oacc0[2] + db.z, oacc0[3] + db.w);
    float4 o1 = make_float4(oacc1[0] + db.x, oacc1[1] + db.y, oacc1[2] + db.z, oacc1[3] + db.w);
    *reinterpret_cast<float4*>(out + ((size_t)b * SS + s0 + r0) * DD + tx4) = o0;
    *reinterpret_cast<float4*>(out + ((size_t)b * SS + s0 + r1) * DD + tx4) = o1;
}

extern "C" void kernel_launch(void* const* d_in, const int* in_sizes, int n_in,
                              void* d_out, int out_size, void* d_ws, size_t ws_size,
                              hipStream_t stream) {
    const float* query   = (const float*)d_in[0];
    const float* key     = (const float*)d_in[1];
    const float* value   = (const float*)d_in[2];
    // d_in[3] attn_mask: unused by the reference math
    const float* wq_w    = (const float*)d_in[4];
    const float* wq_b    = (const float*)d_in[5];
    const float* wk_w    = (const float*)d_in[6];
    const float* wk_b    = (const float*)d_in[7];
    const float* wv_w    = (const float*)d_in[8];
    const float* wv_b    = (const float*)d_in[9];
    const float* dense_w = (const float*)d_in[10];
    const float* dense_b = (const float*)d_in[11];
    float* out = (float*)d_out;

    float* ws    = (float*)d_ws;
    float* kv    = ws;
    float* kvs   = ws + 262144;
    float* ksum  = ws + 524288;
    float* kssum = ws + 528384;

    hipLaunchKernelGGL(k_zero, dim3(520), dim3(256), 0, stream, ws);
    hipLaunchKernelGGL(k_phase1, dim3(NC, HH, BB), dim3(256), 0, stream,
                       key, value, wk_w, wk_b, wv_w, wv_b, kv, kvs, ksum, kssum);
    hipLaunchKernelGGL(k_phase2, dim3(SS / TS2, BB), dim3(256), 0, stream,
                       query, wq_w, wq_b, kv, kvs, ksum, kssum, dense_w, dense_b, out);
}

// Round 2
// 240.316 us; speedup vs baseline: 1.6542x; 1.6542x over previous
//
#include <hip/hip_runtime.h>
#include <math.h>

// Problem constants
#define BB 4
#define SS 4096
#define DD 64
#define HH 16
#define PI_C 3.1415f

// ---------------------------------------------------------------------------
// ws layout (bytes):
//   0        : kvT   fp32 [64bh][z*64+x]   1,048,576
//   1048576  : kvsT  fp32 [64bh][z*64+x]   1,048,576
//   2097152  : ksum  fp32 [64bh][64]          16,384
//   2113536  : kssum fp32 [64bh][64]          16,384
//   2129920  : kvb   bf16 [64bh][z*64+x]     524,288
//   2654208  : kvsb  bf16                    524,288
//   3178496  : wqTb  bf16 [h][x][d]          131,072
//   3309568  : wkTb  bf16                    131,072
//   3440640  : wvTb  bf16                    131,072
//   3571712  : wdTb  bf16 [h][c][zz]         131,072
//   total ~3.7 MB
// ---------------------------------------------------------------------------

typedef __attribute__((ext_vector_type(8))) short short8;   // 8 x bf16 frag
typedef __attribute__((ext_vector_type(4))) float f32x4;    // MFMA C/D frag

#define MFMA(a, b, c) __builtin_amdgcn_mfma_f32_16x16x32_bf16(a, b, c, 0, 0, 0)

__device__ __forceinline__ short f2bf(float f) {
    union { float f; unsigned u; } v; v.f = f;
    unsigned r = v.u + 0x7FFFu + ((v.u >> 16) & 1u);   // round-to-nearest-even
    return (short)(r >> 16);
}
__device__ __forceinline__ float bf2f(short s) {
    union { unsigned u; float f; } v;
    v.u = ((unsigned)(unsigned short)s) << 16;
    return v.f;
}
__device__ __forceinline__ short8 cvt8(float4 a, float4 b) {
    short8 r;
    r[0] = f2bf(a.x); r[1] = f2bf(a.y); r[2] = f2bf(a.z); r[3] = f2bf(a.w);
    r[4] = f2bf(b.x); r[5] = f2bf(b.y); r[6] = f2bf(b.z); r[7] = f2bf(b.w);
    return r;
}
__device__ __forceinline__ float elu1(float x) { return x > 0.f ? x + 1.f : __expf(x); }
__device__ __forceinline__ void st4(short* p, short a, short b, short c, short d) {
    union { uint2 u; short s[4]; } x;
    x.s[0] = a; x.s[1] = b; x.s[2] = c; x.s[3] = d;
    *reinterpret_cast<uint2*>(p) = x.u;
}

// ---------------------------------------------------------------------------
__global__ __launch_bounds__(256) void k_zero(float* __restrict__ p) {
    int i = blockIdx.x * 256 + threadIdx.x;   // 520*256 float4 = 532480 floats
    reinterpret_cast<float4*>(p)[i] = make_float4(0.f, 0.f, 0.f, 0.f);
}

// Transpose + bf16-convert weights: wq/wk/wv (64 x 1024) and dense_w (1024 x 64)
// into per-head [out_col][in_dim] layout so MFMA B-frags are contiguous 16B loads.
__global__ __launch_bounds__(256) void k_prep(
    const float* __restrict__ wq, const float* __restrict__ wk,
    const float* __restrict__ wv, const float* __restrict__ wd,
    short* __restrict__ dst)
{
    const int h = blockIdx.x, y = blockIdx.y, t = threadIdx.x;
    const float* src = (y == 0) ? wq : (y == 1) ? wk : (y == 2) ? wv : wd;
    const int rs = (y < 3) ? 1024 : 64;
    const size_t srcbase = (y < 3) ? (size_t)(h * 64) : (size_t)(h * 4096);
    short* dm = dst + (size_t)y * 65536 + (size_t)h * 4096;
#pragma unroll
    for (int j = 0; j < 4; ++j) {
        int idx = j * 1024 + t * 4;
        int r = idx >> 6, c = idx & 63;
        float4 v = *reinterpret_cast<const float4*>(src + (size_t)r * rs + srcbase + c);
        dm[(c + 0) * 64 + r] = f2bf(v.x);
        dm[(c + 1) * 64 + r] = f2bf(v.y);
        dm[(c + 2) * 64 + r] = f2bf(v.z);
        dm[(c + 3) * 64 + r] = f2bf(v.w);
    }
}

// Convert fp32 kv/kvs accumulators -> bf16 for phase-2 B-frag loads.
__global__ __launch_bounds__(256) void k_cvt(const float* __restrict__ src,
                                             short* __restrict__ dst) {
    int i = blockIdx.x * 256 + threadIdx.x;   // 512*256*4 = 524288 elements
    float4 v = reinterpret_cast<const float4*>(src)[i];
    st4(dst + (size_t)i * 4, f2bf(v.x), f2bf(v.y), f2bf(v.z), f2bf(v.w));
}

// ---------------------------------------------------------------------------
// Phase 1: project K,V (MFMA) -> k'(elu+1), v, v*sin tiles in LDS (transposed,
// bf16) -> kv/kvs GEMM (MFMA, K=s) -> fp32 atomic commit; ksum/kssum via VALU.
__global__ __launch_bounds__(256, 2) void k_phase1(
    const float* __restrict__ key, const float* __restrict__ value,
    const float* __restrict__ wk_b, const float* __restrict__ wv_b,
    const short* __restrict__ wkTb, const short* __restrict__ wvTb,
    float* __restrict__ kvT, float* __restrict__ kvsT,
    float* __restrict__ ksum, float* __restrict__ kssum)
{
    const int chunk = blockIdx.x, h = blockIdx.y, b = blockIdx.z;
    const int t = threadIdx.x, w = t >> 6, l = t & 63;
    const int lane15 = l & 15, q8 = (l >> 4) * 8, q4 = (l >> 4) * 4;

    __shared__ short swk[64 * 72], swv[64 * 72];          // weights [x][d]
    __shared__ short kT[64 * 72], vT[64 * 72], vsT[64 * 72]; // tiles [x|z][s]
    __shared__ float ssin[512];
    __shared__ float sbk[64], sbv[64];
    __shared__ float sred[512];

    // stage weights (straight vectorized copy; layout already transposed)
    {
        const short8* gk = reinterpret_cast<const short8*>(wkTb + (size_t)h * 4096);
        const short8* gv = reinterpret_cast<const short8*>(wvTb + (size_t)h * 4096);
#pragma unroll
        for (int cc = 0; cc < 2; ++cc) {
            int c = t * 2 + cc;
            int row = c >> 3, c8 = (c & 7) * 8;
            *reinterpret_cast<short8*>(&swk[row * 72 + c8]) = gk[c];
            *reinterpret_cast<short8*>(&swv[row * 72 + c8]) = gv[c];
        }
    }
    ssin[t]       = __sinf(PI_C * (float)(chunk * 512 + t)       * (1.f / 4096.f));
    ssin[t + 256] = __sinf(PI_C * (float)(chunk * 512 + t + 256) * (1.f / 4096.f));
    if (t < 64) sbk[t] = wk_b[h * 64 + t];
    else if (t < 128) sbv[t - 64] = wv_b[h * 64 + (t - 64)];

    f32x4 ckv[4], ckvs[4];
#pragma unroll
    for (int i = 0; i < 4; ++i) {
        ckv[i]  = (f32x4){0.f, 0.f, 0.f, 0.f};
        ckvs[i] = (f32x4){0.f, 0.f, 0.f, 0.f};
    }
    float aks = 0.f, akss = 0.f;
    __syncthreads();

    for (int it = 0; it < 8; ++it) {
        const int sbase = it * 64;
        // ---- projection: wave w handles rows [sbase + w*16, +16) ----
        f32x4 ckp[4], cvp[4];
#pragma unroll
        for (int i = 0; i < 4; ++i) {
            ckp[i] = (f32x4){0.f, 0.f, 0.f, 0.f};
            cvp[i] = (f32x4){0.f, 0.f, 0.f, 0.f};
        }
        const size_t grow = ((size_t)b * SS + chunk * 512 + sbase + w * 16 + lane15) * 64;
#pragma unroll
        for (int kss = 0; kss < 2; ++kss) {
            const int ks = kss * 32;
            float4 f0 = *reinterpret_cast<const float4*>(key + grow + ks + q8);
            float4 f1 = *reinterpret_cast<const float4*>(key + grow + ks + q8 + 4);
            short8 ak = cvt8(f0, f1);
            float4 g0 = *reinterpret_cast<const float4*>(value + grow + ks + q8);
            float4 g1 = *reinterpret_cast<const float4*>(value + grow + ks + q8 + 4);
            short8 av = cvt8(g0, g1);
#pragma unroll
            for (int nt = 0; nt < 4; ++nt) {
                short8 bk = *reinterpret_cast<const short8*>(&swk[(nt * 16 + lane15) * 72 + ks + q8]);
                short8 bv = *reinterpret_cast<const short8*>(&swv[(nt * 16 + lane15) * 72 + ks + q8]);
                ckp[nt] = MFMA(ak, bk, ckp[nt]);
                cvp[nt] = MFMA(av, bv, cvp[nt]);
            }
        }
        // ---- bias + act + transposed bf16 stores ----
        const int srel = w * 16 + q4;
#pragma unroll
        for (int nt = 0; nt < 4; ++nt) {
            const int x = nt * 16 + lane15;
            const float bk = sbk[x], bv = sbv[x];
            short ek[4], ev[4], es[4];
#pragma unroll
            for (int r = 0; r < 4; ++r) {
                float kk = elu1(ckp[nt][r] + bk);
                float vv = cvp[nt][r] + bv;
                ek[r] = f2bf(kk);
                ev[r] = f2bf(vv);
                es[r] = f2bf(vv * ssin[sbase + srel + r]);
            }
            st4(&kT [x * 72 + srel], ek[0], ek[1], ek[2], ek[3]);
            st4(&vT [x * 72 + srel], ev[0], ev[1], ev[2], ev[3]);
            st4(&vsT[x * 72 + srel], es[0], es[1], es[2], es[3]);
        }
        __syncthreads();
        // ---- kv / kvs GEMM: wave w owns x-tile w ----
#pragma unroll
        for (int kstep = 0; kstep < 2; ++kstep) {
            const int so = kstep * 32;
            short8 a = *reinterpret_cast<const short8*>(&kT[(w * 16 + lane15) * 72 + so + q8]);
#pragma unroll
            for (int nt = 0; nt < 4; ++nt) {
                short8 bv = *reinterpret_cast<const short8*>(&vT [(nt * 16 + lane15) * 72 + so + q8]);
                short8 bs = *reinterpret_cast<const short8*>(&vsT[(nt * 16 + lane15) * 72 + so + q8]);
                ckv[nt]  = MFMA(a, bv, ckv[nt]);
                ckvs[nt] = MFMA(a, bs, ckvs[nt]);
            }
        }
        // ---- ksum / kssum partials (thread: x = l, s-range [w*16,+16)) ----
        {
            short8 k0 = *reinterpret_cast<const short8*>(&kT[l * 72 + w * 16]);
            short8 k1 = *reinterpret_cast<const short8*>(&kT[l * 72 + w * 16 + 8]);
#pragma unroll
            for (int e = 0; e < 8; ++e) {
                float fa = bf2f(k0[e]), fb = bf2f(k1[e]);
                aks  += fa + fb;
                akss += fa * ssin[sbase + w * 16 + e] + fb * ssin[sbase + w * 16 + 8 + e];
            }
        }
        __syncthreads();
    }

    // ---- commit (device-scope atomics over NC=8 chunk blocks) ----
    const size_t bh = (size_t)(b * HH + h);
    float* kvp  = kvT  + bh * 4096;
    float* kvsp = kvsT + bh * 4096;
#pragma unroll
    for (int nt = 0; nt < 4; ++nt) {
        const int z = nt * 16 + lane15;
#pragma unroll
        for (int r = 0; r < 4; ++r) {
            const int x = w * 16 + q4 + r;
            atomicAdd(&kvp [z * 64 + x], ckv[nt][r]);
            atomicAdd(&kvsp[z * 64 + x], ckvs[nt][r]);
        }
    }
    sred[t] = aks; sred[256 + t] = akss;
    __syncthreads();
    if (t < 64) {
        float s = sred[t] + sred[64 + t] + sred[128 + t] + sred[192 + t];
        atomicAdd(&ksum[bh * 64 + t], s);
    } else if (t < 128) {
        int tt = t - 64;
        float s = sred[256 + tt] + sred[320 + tt] + sred[384 + tt] + sred[448 + tt];
        atomicAdd(&kssum[bh * 64 + tt], s);
    }
}

// ---------------------------------------------------------------------------
// Phase 2: Q-proj (MFMA) -> elu -> num GEMMs vs bf16 kv/kvs (global B-frags)
// -> den (VALU + shfl) -> combine -> dense GEMM accumulated over heads.
__global__ __launch_bounds__(256, 4) void k_phase2(
    const float* __restrict__ query, const float* __restrict__ wq_b,
    const short* __restrict__ wqTb,
    const short* __restrict__ kvb, const short* __restrict__ kvsb,
    const float* __restrict__ ksum, const float* __restrict__ kssum,
    const short* __restrict__ wdTb, const float* __restrict__ dense_b,
    float* __restrict__ out)
{
    const int st = blockIdx.x, b = blockIdx.y;
    const int s0 = st * 32;
    const int t = threadIdx.x, w = t >> 6, l = t & 63;
    const int lane15 = l & 15, q8 = (l >> 4) * 8, q4 = (l >> 4) * 4;
    const int mt = w & 1, ng = w >> 1;   // wave -> (s-half, col-half)

    __shared__ short sqin[32 * 72], sqp[32 * 72], sO[32 * 72];
    __shared__ float scc[32], sks[64], skss[64], sdb[64];

    // stage query tile (fp32 -> bf16, s-major)
    {
        int row = t >> 3, c8 = (t & 7) * 8;
        const float* qp = query + ((size_t)b * SS + s0 + row) * 64 + c8;
        float4 f0 = *reinterpret_cast<const float4*>(qp);
        float4 f1 = *reinterpret_cast<const float4*>(qp + 4);
        *reinterpret_cast<short8*>(&sqin[row * 72 + c8]) = cvt8(f0, f1);
    }
    if (t < 32) {
        float p = PI_C * (float)(s0 + t) * (1.f / 4096.f);
        scc[t] = __cosf(p) + __sinf(p);
    }
    if (t >= 64 && t < 128) sdb[t - 64] = dense_b[t - 64];
    f32x4 cd[2];
    cd[0] = (f32x4){0.f, 0.f, 0.f, 0.f};
    cd[1] = (f32x4){0.f, 0.f, 0.f, 0.f};
    __syncthreads();

    for (int h = 0; h < HH; ++h) {
        const size_t bh = (size_t)(b * HH + h);
        // per-head staging (reads occur after barrier X below)
        if (t < 64) sks[t] = ksum[bh * 64 + t];
        else if (t < 128) skss[t - 64] = kssum[bh * 64 + (t - 64)];

        // ---- Q projection ----
        f32x4 cq[2];
        cq[0] = (f32x4){0.f, 0.f, 0.f, 0.f};
        cq[1] = (f32x4){0.f, 0.f, 0.f, 0.f};
        const short* wqh = wqTb + (size_t)h * 4096;
#pragma unroll
        for (int kss = 0; kss < 2; ++kss) {
            const int ks = kss * 32;
            short8 a = *reinterpret_cast<const short8*>(&sqin[(mt * 16 + lane15) * 72 + ks + q8]);
#pragma unroll
            for (int n = 0; n < 2; ++n) {
                const int nt = ng * 2 + n;
                short8 bb = *reinterpret_cast<const short8*>(wqh + (nt * 16 + lane15) * 64 + ks + q8);
                cq[n] = MFMA(a, bb, cq[n]);
            }
        }
        // bias (direct global, avoids LDS race) + elu + store q' (s-major)
#pragma unroll
        for (int n = 0; n < 2; ++n) {
            const int x = (ng * 2 + n) * 16 + lane15;
            const float bq = wq_b[h * 64 + x];
#pragma unroll
            for (int r = 0; r < 4; ++r) {
                sqp[(mt * 16 + q4 + r) * 72 + x] = f2bf(elu1(cq[n][r] + bq));
            }
        }
        __syncthreads();   // X: q' complete

        // ---- denominator (per-wave own rows; no extra barrier) ----
        float invd;
        {
            const int sl = mt * 16 + (l >> 2);
            const int x0 = (l & 3) * 16;
            const float ccs = scc[sl];
            short8 qa = *reinterpret_cast<const short8*>(&sqp[sl * 72 + x0]);
            short8 qb = *reinterpret_cast<const short8*>(&sqp[sl * 72 + x0 + 8]);
            float dsum = 0.f;
#pragma unroll
            for (int e = 0; e < 8; ++e) {
                dsum += bf2f(qa[e]) * (sks[x0 + e]     + ccs * skss[x0 + e]);
                dsum += bf2f(qb[e]) * (sks[x0 + 8 + e] + ccs * skss[x0 + 8 + e]);
            }
            dsum += __shfl_xor(dsum, 1);
            dsum += __shfl_xor(dsum, 2);
            invd = 1.f / (dsum + 1e-5f);
        }
        float invq[4], ccq[4];
#pragma unroll
        for (int r = 0; r < 4; ++r) {
            invq[r] = __shfl(invd, (q4 + r) * 4);
            ccq[r]  = scc[mt * 16 + q4 + r];
        }

        // ---- numerator GEMMs (B-frags direct from global bf16 kv/kvs) ----
        f32x4 ckv[2], ckvs[2];
        ckv[0] = ckv[1] = (f32x4){0.f, 0.f, 0.f, 0.f};
        ckvs[0] = ckvs[1] = (f32x4){0.f, 0.f, 0.f, 0.f};
        const short* kvh  = kvb  + bh * 4096;
        const short* kvsh = kvsb + bh * 4096;
#pragma unroll
        for (int kss = 0; kss < 2; ++kss) {
            const int ks = kss * 32;
            short8 a = *reinterpret_cast<const short8*>(&sqp[(mt * 16 + lane15) * 72 + ks + q8]);
#pragma unroll
            for (int n = 0; n < 2; ++n) {
                const int nt = ng * 2 + n;
                short8 b1 = *reinterpret_cast<const short8*>(kvh  + (nt * 16 + lane15) * 64 + ks + q8);
                short8 b2 = *reinterpret_cast<const short8*>(kvsh + (nt * 16 + lane15) * 64 + ks + q8);
                ckv[n]  = MFMA(a, b1, ckv[n]);
                ckvs[n] = MFMA(a, b2, ckvs[n]);
            }
        }
        // combine + store O (bf16, s-major)
#pragma unroll
        for (int n = 0; n < 2; ++n) {
            const int z = (ng * 2 + n) * 16 + lane15;
#pragma unroll
            for (int r = 0; r < 4; ++r) {
                float o = (ckv[n][r] + ccq[r] * ckvs[n][r]) * invq[r];
                sO[(mt * 16 + q4 + r) * 72 + z] = f2bf(o);
            }
        }
        __syncthreads();   // Y: O complete

        // ---- dense GEMM, accumulate across heads ----
        const short* wdh = wdTb + (size_t)h * 4096;
#pragma unroll
        for (int kss = 0; kss < 2; ++kss) {
            const int ks = kss * 32;
            short8 a = *reinterpret_cast<const short8*>(&sO[(mt * 16 + lane15) * 72 + ks + q8]);
#pragma unroll
            for (int n = 0; n < 2; ++n) {
                const int nt = ng * 2 + n;
                short8 bb = *reinterpret_cast<const short8*>(wdh + (nt * 16 + lane15) * 64 + ks + q8);
                cd[n] = MFMA(a, bb, cd[n]);
            }
        }
    }

    // epilogue: bias + direct fp32 store
#pragma unroll
    for (int n = 0; n < 2; ++n) {
        const int c = (ng * 2 + n) * 16 + lane15;
        const float bias = sdb[c];
#pragma unroll
        for (int r = 0; r < 4; ++r) {
            out[((size_t)b * SS + s0 + mt * 16 + q4 + r) * 64 + c] = cd[n][r] + bias;
        }
    }
}

// ---------------------------------------------------------------------------
extern "C" void kernel_launch(void* const* d_in, const int* in_sizes, int n_in,
                              void* d_out, int out_size, void* d_ws, size_t ws_size,
                              hipStream_t stream) {
    const float* query   = (const float*)d_in[0];
    const float* key     = (const float*)d_in[1];
    const float* value   = (const float*)d_in[2];
    // d_in[3] attn_mask unused
    const float* wq_w    = (const float*)d_in[4];
    const float* wq_b    = (const float*)d_in[5];
    const float* wk_w    = (const float*)d_in[6];
    const float* wk_b    = (const float*)d_in[7];
    const float* wv_w    = (const float*)d_in[8];
    const float* wv_b    = (const float*)d_in[9];
    const float* dense_w = (const float*)d_in[10];
    const float* dense_b = (const float*)d_in[11];
    float* out = (float*)d_out;

    char* ws = (char*)d_ws;
    float* kvT   = (float*)(ws);
    float* kvsT  = (float*)(ws + 1048576);
    float* ksum  = (float*)(ws + 2097152);
    float* kssum = (float*)(ws + 2113536);
    short* kvb   = (short*)(ws + 2129920);
    short* kvsb  = (short*)(ws + 2654208);
    short* wT    = (short*)(ws + 3178496);   // wq|wk|wv|wd, 65536 shorts each
    short* wqTb  = wT;
    short* wkTb  = wT + 65536;
    short* wvTb  = wT + 131072;
    short* wdTb  = wT + 196608;

    hipLaunchKernelGGL(k_zero, dim3(520), dim3(256), 0, stream, kvT);
    hipLaunchKernelGGL(k_prep, dim3(16, 4), dim3(256), 0, stream,
                       wq_w, wk_w, wv_w, dense_w, wT);
    hipLaunchKernelGGL(k_phase1, dim3(8, HH, BB), dim3(256), 0, stream,
                       key, value, wk_b, wv_b, wkTb, wvTb, kvT, kvsT, ksum, kssum);
    hipLaunchKernelGGL(k_cvt, dim3(512), dim3(256), 0, stream, kvT, kvb);
    hipLaunchKernelGGL(k_phase2, dim3(128, BB), dim3(256), 0, stream,
                       query, wq_b, wqTb, kvb, kvsb, ksum, kssum, wdTb, dense_b, out);
}

// Round 3
// 173.665 us; speedup vs baseline: 2.2891x; 1.3838x over previous
//
#include <hip/hip_runtime.h>
#include <math.h>

// Problem constants
#define BB 4
#define SS 4096
#define DD 64
#define HH 16
#define PI_C 3.1415f

// ---------------------------------------------------------------------------
// ws layout (bytes):
//   0        : pkv   fp32 [8][64bh][z*64+x]   8,388,608
//   8388608  : pkvs  fp32 [8][64bh][z*64+x]   8,388,608
//   16777216 : pks   fp32 [8][64bh][128]        262,144   (ksum|kssum)
//   17039360 : kvb   bf16 [64bh][z*64+x]        524,288
//   17563648 : kvsb  bf16                       524,288
//   18087936 : ksums fp32 [64bh][128]            32,768
//   18120704 : wT    bf16 wq|wk|wv|wd x 65536   524,288
//   total ~18.6 MB
// ---------------------------------------------------------------------------

typedef __attribute__((ext_vector_type(8))) short short8;   // 8 x bf16 frag
typedef __attribute__((ext_vector_type(4))) float f32x4;    // MFMA C/D frag

#define MFMA(a, b, c) __builtin_amdgcn_mfma_f32_16x16x32_bf16(a, b, c, 0, 0, 0)

__device__ __forceinline__ short f2bf(float f) {
    union { float f; unsigned u; } v; v.f = f;
    unsigned r = v.u + 0x7FFFu + ((v.u >> 16) & 1u);   // round-to-nearest-even
    return (short)(r >> 16);
}
__device__ __forceinline__ float bf2f(short s) {
    union { unsigned u; float f; } v;
    v.u = ((unsigned)(unsigned short)s) << 16;
    return v.f;
}
__device__ __forceinline__ short8 cvt8(float4 a, float4 b) {
    short8 r;
    r[0] = f2bf(a.x); r[1] = f2bf(a.y); r[2] = f2bf(a.z); r[3] = f2bf(a.w);
    r[4] = f2bf(b.x); r[5] = f2bf(b.y); r[6] = f2bf(b.z); r[7] = f2bf(b.w);
    return r;
}
__device__ __forceinline__ float elu1(float x) { return x > 0.f ? x + 1.f : __expf(x); }
__device__ __forceinline__ void st4(short* p, short a, short b, short c, short d) {
    union { uint2 u; short s[4]; } x;
    x.s[0] = a; x.s[1] = b; x.s[2] = c; x.s[3] = d;
    *reinterpret_cast<uint2*>(p) = x.u;
}

// ---------------------------------------------------------------------------
// Transpose + bf16-convert weights: wq/wk/wv (64 x 1024) and dense_w (1024 x 64)
// into per-head [out_col][in_dim] layout so MFMA B-frags are contiguous 16B loads.
__global__ __launch_bounds__(256) void k_prep(
    const float* __restrict__ wq, const float* __restrict__ wk,
    const float* __restrict__ wv, const float* __restrict__ wd,
    short* __restrict__ dst)
{
    const int h = blockIdx.x, y = blockIdx.y, t = threadIdx.x;
    const float* src = (y == 0) ? wq : (y == 1) ? wk : (y == 2) ? wv : wd;
    const int rs = (y < 3) ? 1024 : 64;
    const size_t srcbase = (y < 3) ? (size_t)(h * 64) : (size_t)(h * 4096);
    short* dm = dst + (size_t)y * 65536 + (size_t)h * 4096;
#pragma unroll
    for (int j = 0; j < 4; ++j) {
        int idx = j * 1024 + t * 4;
        int r = idx >> 6, c = idx & 63;
        float4 v = *reinterpret_cast<const float4*>(src + (size_t)r * rs + srcbase + c);
        dm[(c + 0) * 64 + r] = f2bf(v.x);
        dm[(c + 1) * 64 + r] = f2bf(v.y);
        dm[(c + 2) * 64 + r] = f2bf(v.z);
        dm[(c + 3) * 64 + r] = f2bf(v.w);
    }
}

// ---------------------------------------------------------------------------
// Phase 1: project K,V (MFMA, weight B-frags held in registers) -> transposed
// bf16 tiles in LDS -> kv/kvs GEMM with SWAPPED operands (A=v, B=k') so the
// C-layout is [z][x] with x in lane15 -> coalesced non-atomic partial stores.
__global__ __launch_bounds__(256, 2) void k_phase1(
    const float* __restrict__ key, const float* __restrict__ value,
    const float* __restrict__ wk_b, const float* __restrict__ wv_b,
    const short* __restrict__ wkTb, const short* __restrict__ wvTb,
    float* __restrict__ pkv, float* __restrict__ pkvs,
    float* __restrict__ pks)
{
    const int chunk = blockIdx.x, h = blockIdx.y, b = blockIdx.z;
    const int t = threadIdx.x, w = t >> 6, l = t & 63;
    const int lane15 = l & 15, q8 = (l >> 4) * 8, q4 = (l >> 4) * 4;

    __shared__ short kT[64 * 72], vT[64 * 72], vsT[64 * 72];   // [x|z][s]
    __shared__ float ssin[512];
    __shared__ float sbk[64], sbv[64];
    __shared__ float sred[512];

    // projection weight B-frags -> registers (once per block, L2-hot)
    short8 bkf[2][4], bvf[2][4];
    {
        const short* wkh = wkTb + (size_t)h * 4096;
        const short* wvh = wvTb + (size_t)h * 4096;
#pragma unroll
        for (int kss = 0; kss < 2; ++kss)
#pragma unroll
            for (int nt = 0; nt < 4; ++nt) {
                bkf[kss][nt] = *reinterpret_cast<const short8*>(wkh + (nt * 16 + lane15) * 64 + kss * 32 + q8);
                bvf[kss][nt] = *reinterpret_cast<const short8*>(wvh + (nt * 16 + lane15) * 64 + kss * 32 + q8);
            }
    }
    ssin[t]       = __sinf(PI_C * (float)(chunk * 512 + t)       * (1.f / 4096.f));
    ssin[t + 256] = __sinf(PI_C * (float)(chunk * 512 + t + 256) * (1.f / 4096.f));
    if (t < 64) sbk[t] = wk_b[h * 64 + t];
    else if (t < 128) sbv[t - 64] = wv_b[h * 64 + (t - 64)];

    // prefetch K/V rows for iter 0
    float4 kf0, kf1, kf2, kf3, vf0, vf1, vf2, vf3;
    {
        const size_t g = ((size_t)b * SS + chunk * 512 + w * 16 + lane15) * 64 + q8;
        kf0 = *reinterpret_cast<const float4*>(key + g);
        kf1 = *reinterpret_cast<const float4*>(key + g + 4);
        kf2 = *reinterpret_cast<const float4*>(key + g + 32);
        kf3 = *reinterpret_cast<const float4*>(key + g + 36);
        vf0 = *reinterpret_cast<const float4*>(value + g);
        vf1 = *reinterpret_cast<const float4*>(value + g + 4);
        vf2 = *reinterpret_cast<const float4*>(value + g + 32);
        vf3 = *reinterpret_cast<const float4*>(value + g + 36);
    }

    f32x4 ckv[4], ckvs[4];
#pragma unroll
    for (int i = 0; i < 4; ++i) {
        ckv[i]  = (f32x4){0.f, 0.f, 0.f, 0.f};
        ckvs[i] = (f32x4){0.f, 0.f, 0.f, 0.f};
    }
    float aks = 0.f, akss = 0.f;
    __syncthreads();

    for (int it = 0; it < 8; ++it) {
        const int sbase = it * 64;
        // ---- projection: wave w handles rows [sbase + w*16, +16) ----
        f32x4 ckp[4], cvp[4];
#pragma unroll
        for (int i = 0; i < 4; ++i) {
            ckp[i] = (f32x4){0.f, 0.f, 0.f, 0.f};
            cvp[i] = (f32x4){0.f, 0.f, 0.f, 0.f};
        }
        {
            short8 ak0 = cvt8(kf0, kf1), ak1 = cvt8(kf2, kf3);
            short8 av0 = cvt8(vf0, vf1), av1 = cvt8(vf2, vf3);
#pragma unroll
            for (int nt = 0; nt < 4; ++nt) {
                ckp[nt] = MFMA(ak0, bkf[0][nt], ckp[nt]);
                cvp[nt] = MFMA(av0, bvf[0][nt], cvp[nt]);
                ckp[nt] = MFMA(ak1, bkf[1][nt], ckp[nt]);
                cvp[nt] = MFMA(av1, bvf[1][nt], cvp[nt]);
            }
        }
        // ---- bias + act + transposed bf16 stores ----
        const int srel = w * 16 + q4;
#pragma unroll
        for (int nt = 0; nt < 4; ++nt) {
            const int x = nt * 16 + lane15;
            const float bk = sbk[x], bv = sbv[x];
            short ek[4], ev[4], es[4];
#pragma unroll
            for (int r = 0; r < 4; ++r) {
                float kk = elu1(ckp[nt][r] + bk);
                float vv = cvp[nt][r] + bv;
                ek[r] = f2bf(kk);
                ev[r] = f2bf(vv);
                es[r] = f2bf(vv * ssin[sbase + srel + r]);
            }
            st4(&kT [x * 72 + srel], ek[0], ek[1], ek[2], ek[3]);
            st4(&vT [x * 72 + srel], ev[0], ev[1], ev[2], ev[3]);
            st4(&vsT[x * 72 + srel], es[0], es[1], es[2], es[3]);
        }
        __syncthreads();
        // ---- prefetch next iter's K/V (overlaps with kv GEMM below) ----
        if (it < 7) {
            const size_t g = ((size_t)b * SS + chunk * 512 + (it + 1) * 64 + w * 16 + lane15) * 64 + q8;
            kf0 = *reinterpret_cast<const float4*>(key + g);
            kf1 = *reinterpret_cast<const float4*>(key + g + 4);
            kf2 = *reinterpret_cast<const float4*>(key + g + 32);
            kf3 = *reinterpret_cast<const float4*>(key + g + 36);
            vf0 = *reinterpret_cast<const float4*>(value + g);
            vf1 = *reinterpret_cast<const float4*>(value + g + 4);
            vf2 = *reinterpret_cast<const float4*>(value + g + 32);
            vf3 = *reinterpret_cast<const float4*>(value + g + 36);
        }
        // ---- kv / kvs GEMM, swapped operands: A=v (m=z), B=k' (n=x) ----
#pragma unroll
        for (int kstep = 0; kstep < 2; ++kstep) {
            const int so = kstep * 32;
            short8 aV  = *reinterpret_cast<const short8*>(&vT [(w * 16 + lane15) * 72 + so + q8]);
            short8 aVS = *reinterpret_cast<const short8*>(&vsT[(w * 16 + lane15) * 72 + so + q8]);
#pragma unroll
            for (int nt = 0; nt < 4; ++nt) {
                short8 bK = *reinterpret_cast<const short8*>(&kT[(nt * 16 + lane15) * 72 + so + q8]);
                ckv[nt]  = MFMA(aV,  bK, ckv[nt]);
                ckvs[nt] = MFMA(aVS, bK, ckvs[nt]);
            }
        }
        // ---- ksum / kssum partials (thread: x = l, s-range [w*16,+16)) ----
        {
            short8 k0 = *reinterpret_cast<const short8*>(&kT[l * 72 + w * 16]);
            short8 k1 = *reinterpret_cast<const short8*>(&kT[l * 72 + w * 16 + 8]);
#pragma unroll
            for (int e = 0; e < 8; ++e) {
                float fa = bf2f(k0[e]), fb = bf2f(k1[e]);
                aks  += fa + fb;
                akss += fa * ssin[sbase + w * 16 + e] + fb * ssin[sbase + w * 16 + 8 + e];
            }
        }
        __syncthreads();
    }

    // ---- commit: coalesced non-atomic partial stores ([z][x], x = lane15) ----
    const int bh = b * HH + h;
    const size_t pbase = ((size_t)(chunk * 64) + bh) * 4096;
#pragma unroll
    for (int nt = 0; nt < 4; ++nt) {
        const int x = nt * 16 + lane15;
#pragma unroll
        for (int r = 0; r < 4; ++r) {
            const int z = w * 16 + q4 + r;
            pkv [pbase + z * 64 + x] = ckv[nt][r];
            pkvs[pbase + z * 64 + x] = ckvs[nt][r];
        }
    }
    sred[t] = aks; sred[256 + t] = akss;
    __syncthreads();
    if (t < 64) {
        pks[((size_t)(chunk * 64) + bh) * 128 + t] =
            sred[t] + sred[64 + t] + sred[128 + t] + sred[192 + t];
    } else if (t < 128) {
        int tt = t - 64;
        pks[((size_t)(chunk * 64) + bh) * 128 + t] =
            sred[256 + tt] + sred[320 + tt] + sred[384 + tt] + sred[448 + tt];
    }
}

// ---------------------------------------------------------------------------
// Reduce 8 chunk partials -> bf16 kv/kvs + fp32 ksums.
__global__ __launch_bounds__(256) void k_reduce(
    const float* __restrict__ pkv, const float* __restrict__ pkvs,
    const float* __restrict__ pks,
    short* __restrict__ kvb, short* __restrict__ kvsb,
    float* __restrict__ ksums)
{
    const int blk = blockIdx.x, t = threadIdx.x;
    if (blk < 512) {
        const float* src = (blk < 256) ? pkv : pkvs;
        short* dst = (blk < 256) ? kvb : kvsb;
        const int o4 = (blk & 255) * 256 + t;          // float4 index, 0..65535
        float4 s = make_float4(0.f, 0.f, 0.f, 0.f);
#pragma unroll
        for (int c = 0; c < 8; ++c) {
            float4 v = reinterpret_cast<const float4*>(src + (size_t)c * 262144)[o4];
            s.x += v.x; s.y += v.y; s.z += v.z; s.w += v.w;
        }
        st4(dst + (size_t)o4 * 4, f2bf(s.x), f2bf(s.y), f2bf(s.z), f2bf(s.w));
    } else {
        const int g = (blk - 512) * 256 + t;           // float4 index, 0..2047
        float4 s = make_float4(0.f, 0.f, 0.f, 0.f);
#pragma unroll
        for (int c = 0; c < 8; ++c) {
            float4 v = reinterpret_cast<const float4*>(pks + (size_t)c * 8192)[g];
            s.x += v.x; s.y += v.y; s.z += v.z; s.w += v.w;
        }
        reinterpret_cast<float4*>(ksums)[g] = s;
    }
}

// ---------------------------------------------------------------------------
// Phase 2: 16-row s-tiles (grid 1024 -> 4 blocks/CU). Wave w owns col-tile w.
__global__ __launch_bounds__(256, 4) void k_phase2(
    const float* __restrict__ query, const float* __restrict__ wq_b,
    const short* __restrict__ wqTb,
    const short* __restrict__ kvb, const short* __restrict__ kvsb,
    const float* __restrict__ ksums,
    const short* __restrict__ wdTb, const float* __restrict__ dense_b,
    float* __restrict__ out)
{
    const int st = blockIdx.x, b = blockIdx.y;
    const int s0 = st * 16;
    const int t = threadIdx.x, w = t >> 6, l = t & 63;
    const int lane15 = l & 15, q8 = (l >> 4) * 8, q4 = (l >> 4) * 4;
    const int x = w * 16 + lane15;     // this wave's output column (all sections)

    __shared__ short sqin[16 * 72], sqp[16 * 72], sO[16 * 72];
    __shared__ float sbq[1024];
    __shared__ float sks2[128];
    __shared__ float scc[16], sdb[64];

    // stage q tile (fp32 -> bf16, s-major)
    if (t < 128) {
        int row = t >> 3, c8 = (t & 7) * 8;
        const float* qp = query + ((size_t)b * SS + s0 + row) * 64 + c8;
        float4 f0 = *reinterpret_cast<const float4*>(qp);
        float4 f1 = *reinterpret_cast<const float4*>(qp + 4);
        *reinterpret_cast<short8*>(&sqin[row * 72 + c8]) = cvt8(f0, f1);
    }
    for (int i = t; i < 1024; i += 256) sbq[i] = wq_b[i];
    if (t < 16) {
        float p = PI_C * (float)(s0 + t) * (1.f / 4096.f);
        scc[t] = __cosf(p) + __sinf(p);
    }
    if (t >= 192) sdb[t - 192] = dense_b[t - 192];
    f32x4 cd = (f32x4){0.f, 0.f, 0.f, 0.f};
    __syncthreads();

    for (int h = 0; h < HH; ++h) {
        const size_t bh = (size_t)(b * HH + h);
        if (t < 128) sks2[t] = ksums[bh * 128 + t];    // read after barrier X

        // ---- Q projection (one 16x16 col-tile per wave) ----
        f32x4 cq = (f32x4){0.f, 0.f, 0.f, 0.f};
        const short* wqh = wqTb + bh % HH * 0 + (size_t)h * 4096;
#pragma unroll
        for (int kss = 0; kss < 2; ++kss) {
            short8 a = *reinterpret_cast<const short8*>(&sqin[lane15 * 72 + kss * 32 + q8]);
            short8 bb = *reinterpret_cast<const short8*>(wqh + x * 64 + kss * 32 + q8);
            cq = MFMA(a, bb, cq);
        }
        // prefetch num B-frags (independent of LDS; overlap barrier)
        short8 nb1[2], nb2[2];
#pragma unroll
        for (int kss = 0; kss < 2; ++kss) {
            nb1[kss] = *reinterpret_cast<const short8*>(kvb  + bh * 4096 + x * 64 + kss * 32 + q8);
            nb2[kss] = *reinterpret_cast<const short8*>(kvsb + bh * 4096 + x * 64 + kss * 32 + q8);
        }
        // bias + elu + store q' (s-major)
        {
            const float bq = sbq[h * 64 + x];
#pragma unroll
            for (int r = 0; r < 4; ++r)
                sqp[(q4 + r) * 72 + x] = f2bf(elu1(cq[r] + bq));
        }
        __syncthreads();   // X: q' complete

        // ---- denominator (each wave redundantly covers all 16 rows) ----
        float invd;
        {
            const int sl = l >> 2;
            const int x0 = (l & 3) * 16;
            const float ccs = scc[sl];
            short8 qa = *reinterpret_cast<const short8*>(&sqp[sl * 72 + x0]);
            short8 qb = *reinterpret_cast<const short8*>(&sqp[sl * 72 + x0 + 8]);
            float dsum = 0.f;
#pragma unroll
            for (int e = 0; e < 8; ++e) {
                dsum += bf2f(qa[e]) * (sks2[x0 + e]     + ccs * sks2[64 + x0 + e]);
                dsum += bf2f(qb[e]) * (sks2[x0 + 8 + e] + ccs * sks2[64 + x0 + 8 + e]);
            }
            dsum += __shfl_xor(dsum, 1);
            dsum += __shfl_xor(dsum, 2);
            invd = 1.f / (dsum + 1e-5f);
        }
        float invq[4], ccq[4];
#pragma unroll
        for (int r = 0; r < 4; ++r) {
            invq[r] = __shfl(invd, (q4 + r) * 4);
            ccq[r]  = scc[q4 + r];
        }

        // ---- numerator GEMMs ----
        f32x4 ckv = (f32x4){0.f, 0.f, 0.f, 0.f};
        f32x4 ckvs = (f32x4){0.f, 0.f, 0.f, 0.f};
#pragma unroll
        for (int kss = 0; kss < 2; ++kss) {
            short8 a = *reinterpret_cast<const short8*>(&sqp[lane15 * 72 + kss * 32 + q8]);
            ckv  = MFMA(a, nb1[kss], ckv);
            ckvs = MFMA(a, nb2[kss], ckvs);
        }
        // prefetch dense B-frags
        short8 dbf[2];
#pragma unroll
        for (int kss = 0; kss < 2; ++kss)
            dbf[kss] = *reinterpret_cast<const short8*>(wdTb + (size_t)h * 4096 + x * 64 + kss * 32 + q8);
        // combine + store O (bf16, s-major)
#pragma unroll
        for (int r = 0; r < 4; ++r) {
            float o = (ckv[r] + ccq[r] * ckvs[r]) * invq[r];
            sO[(q4 + r) * 72 + x] = f2bf(o);
        }
        __syncthreads();   // Y: O complete

        // ---- dense GEMM, accumulate across heads ----
#pragma unroll
        for (int kss = 0; kss < 2; ++kss) {
            short8 a = *reinterpret_cast<const short8*>(&sO[lane15 * 72 + kss * 32 + q8]);
            cd = MFMA(a, dbf[kss], cd);
        }
    }

    // epilogue: bias + direct fp32 store
    {
        const float bias = sdb[x];
#pragma unroll
        for (int r = 0; r < 4; ++r)
            out[((size_t)b * SS + s0 + q4 + r) * 64 + x] = cd[r] + bias;
    }
}

// ---------------------------------------------------------------------------
extern "C" void kernel_launch(void* const* d_in, const int* in_sizes, int n_in,
                              void* d_out, int out_size, void* d_ws, size_t ws_size,
                              hipStream_t stream) {
    const float* query   = (const float*)d_in[0];
    const float* key     = (const float*)d_in[1];
    const float* value   = (const float*)d_in[2];
    // d_in[3] attn_mask unused
    const float* wq_w    = (const float*)d_in[4];
    const float* wq_b    = (const float*)d_in[5];
    const float* wk_w    = (const float*)d_in[6];
    const float* wk_b    = (const float*)d_in[7];
    const float* wv_w    = (const float*)d_in[8];
    const float* wv_b    = (const float*)d_in[9];
    const float* dense_w = (const float*)d_in[10];
    const float* dense_b = (const float*)d_in[11];
    float* out = (float*)d_out;

    char* ws = (char*)d_ws;
    float* pkv   = (float*)(ws);
    float* pkvs  = (float*)(ws + 8388608);
    float* pks   = (float*)(ws + 16777216);
    short* kvb   = (short*)(ws + 17039360);
    short* kvsb  = (short*)(ws + 17563648);
    float* ksums = (float*)(ws + 18087936);
    short* wT    = (short*)(ws + 18120704);  // wq|wk|wv|wd, 65536 shorts each
    short* wqTb  = wT;
    short* wkTb  = wT + 65536;
    short* wvTb  = wT + 131072;
    short* wdTb  = wT + 196608;

    hipLaunchKernelGGL(k_prep, dim3(16, 4), dim3(256), 0, stream,
                       wq_w, wk_w, wv_w, dense_w, wT);
    hipLaunchKernelGGL(k_phase1, dim3(8, HH, BB), dim3(256), 0, stream,
                       key, value, wk_b, wv_b, wkTb, wvTb, pkv, pkvs, pks);
    hipLaunchKernelGGL(k_reduce, dim3(520), dim3(256), 0, stream,
                       pkv, pkvs, pks, kvb, kvsb, ksums);
    hipLaunchKernelGGL(k_phase2, dim3(256, BB), dim3(256), 0, stream,
                       query, wq_b, wqTb, kvb, kvsb, ksums, wdTb, dense_b, out);
}